// Round 10
// baseline (13.046 us; speedup 1.0000x reference)
//
#include <hip/hip_runtime.h>
#include <math.h>

#define N2V 32
#define BLOCK 512             // 8 waves: one block per h
#define CHUNK 4096            // 128 b-values x 32 a-values

typedef float v2f __attribute__((ext_vector_type(2)));

__global__ __launch_bounds__(BLOCK) void s4d_vand_kernel(
    const float* __restrict__ C,          // (H, N2, 2)
    const float* __restrict__ log_dt,     // (H,)
    const float* __restrict__ log_A_real, // (H, N2)
    const float* __restrict__ A_imag,     // (H, N2)
    float* __restrict__ K,                // (H, L)
    int L, int chunks_per_h)
{
    __shared__ float4 sC[N2V];            // (x, y, 2*Ceff_r, 2*Ceff_i)
    __shared__ float2 sR2[N2V];           // r = exp(dtA)
    __shared__ float2 sP2[N2V][64];       // (Pr(2i), Pi(2i)) - EVEN b only (512 B/row)
    __shared__ float4 sQ4[N2V][16];       // [n][2w]=(Qr a=4w..4w+3), [n][2w+1]=(-Qi ..)

    const int h     = blockIdx.x / chunks_per_h;
    const int chunk = (blockIdx.x % chunks_per_h) * CHUNK;
    const int t     = threadIdx.x;

    // ---- stage 1: per-n constants (accurate math, one-time) ----
    if (t < N2V) {
        const int n = t;
        const float dt = expf(log_dt[h]);
        const float ar = -expf(log_A_real[h * N2V + n]);  // Re(A)
        const float ai = A_imag[h * N2V + n];             // Im(A)
        const float x = ar * dt;                          // Re(dtA)
        const float y = ai * dt;                          // Im(dtA)
        float sn, cs;
        sincosf(y, &sn, &cs);
        const float e  = expf(x);
        const float wr = e * cs - 1.0f;                   // w = exp(dtA)-1
        const float wi = e * sn;
        const float inv = 1.0f / (ar * ar + ai * ai);     // w/A = w*conj(A)/|A|^2
        const float dr = (wr * ar + wi * ai) * inv;
        const float di = (wi * ar - wr * ai) * inv;
        const float cr = C[(h * N2V + n) * 2 + 0];
        const float ci = C[(h * N2V + n) * 2 + 1];
        sC[n] = make_float4(x, y,
                            2.0f * (cr * dr - ci * di),
                            2.0f * (cr * di + ci * dr));
        sR2[n] = make_float2(e * cs, e * sn);             // r = exp(dtA)
    }
    __syncthreads();

    // ---- stage 2a: even-b P table, 2048 float2 entries (4 per thread) ----
#pragma unroll
    for (int m = 0; m < 4; ++m) {
        const int e = t + m * BLOCK;          // 0..2047
        const int n = e >> 6;                 // 0..31
        const int i = e & 63;                 // even b = 2i
        const float4 c = sC[n];
        const float fb = (float)(2 * i);
        float sn, cs;
        __sincosf(c.y * fb, &sn, &cs);
        const float ex = __expf(c.x * fb);
        const float ur = ex * cs, ui = ex * sn;           // r^(2i)
        sP2[n][i] = make_float2(c.z * ur - c.w * ui,      // P(2i) = 2Ceff * r^(2i)
                                c.z * ui + c.w * ur);
    }
    // ---- stage 2b: Q tables, (n, w) pairs: 256 workers, 4 Q-values each ----
    if (t < 256) {
        const int n = t >> 3;                 // 0..31
        const int w = t & 7;                  // a-group: a = 4w..4w+3
        const float4 c = sC[n];
        float qr[4], qi[4];
#pragma unroll
        for (int j = 0; j < 4; ++j) {
            const float fl = (float)(chunk + 128 * (4 * w + j));
            float sn, cs;
            __sincosf(c.y * fl, &sn, &cs);
            const float ex = __expf(c.x * fl);
            qr[j] =  ex * cs;
            qi[j] = -ex * sn;
        }
        sQ4[n][2 * w]     = make_float4(qr[0], qr[1], qr[2], qr[3]);
        sQ4[n][2 * w + 1] = make_float4(qi[0], qi[1], qi[2], qi[3]);
    }
    __syncthreads();

    // ---- main: packed-FMA reduction over n, odd-b reconstructed in VALU ----
    const int lane = t & 63;                  // b-pair (2*lane, 2*lane+1)
    const int w    = t >> 6;                  // wave id -> a in {4w..4w+3}

    v2f acc[4];
#pragma unroll
    for (int j = 0; j < 4; ++j) acc[j] = (v2f){0.0f, 0.0f};

    // unroll 2 only: wide unrolls blew VGPR to 256 + spills in round 4.
#pragma unroll 2
    for (int n = 0; n < N2V; ++n) {
        const float2 pp = sP2[n][lane];       // per-lane b64 (even-b P), 512 B/wave
        const float2 rr = sR2[n];             // uniform b64 broadcast
        const float4 qr = sQ4[n][2 * w];      // uniform b128 broadcast
        const float4 qi = sQ4[n][2 * w + 1];  // uniform b128 broadcast
        // odd-b P = even-b P * r  (4 VALU ops)
        const float p1r = fmaf(pp.x, rr.x, -pp.y * rr.y);
        const float p1i = fmaf(pp.x, rr.y,  pp.y * rr.x);
        const v2f prr = {pp.x, p1r};          // (Pr at 2lane, Pr at 2lane+1)
        const v2f pii = {pp.y, p1i};          // (Pi at 2lane, Pi at 2lane+1)
        acc[0] = __builtin_elementwise_fma(prr, (v2f){qr.x, qr.x},
                 __builtin_elementwise_fma(pii, (v2f){qi.x, qi.x}, acc[0]));
        acc[1] = __builtin_elementwise_fma(prr, (v2f){qr.y, qr.y},
                 __builtin_elementwise_fma(pii, (v2f){qi.y, qi.y}, acc[1]));
        acc[2] = __builtin_elementwise_fma(prr, (v2f){qr.z, qr.z},
                 __builtin_elementwise_fma(pii, (v2f){qi.z, qi.z}, acc[2]));
        acc[3] = __builtin_elementwise_fma(prr, (v2f){qr.w, qr.w},
                 __builtin_elementwise_fma(pii, (v2f){qi.w, qi.w}, acc[3]));
    }

    // ---- store: acc[j] = (K(2lane, a), K(2lane+1, a)), a = 4w+j ----
    float* out = K + (size_t)h * L + chunk + 2 * lane;
#pragma unroll
    for (int j = 0; j < 4; ++j) {
        const int a  = 4 * w + j;
        const int l0 = chunk + 2 * lane + 128 * a;
        if (l0 < L)   // L even, l0 even -> the pair fits
            *reinterpret_cast<float2*>(out + (size_t)128 * a) =
                make_float2(acc[j].x, acc[j].y);
    }
}

extern "C" void kernel_launch(void* const* d_in, const int* in_sizes, int n_in,
                              void* d_out, int out_size, void* d_ws, size_t ws_size,
                              hipStream_t stream) {
    // inputs: [0]=L (scalar), [1]=C (H,N2,2), [2]=log_dt (H,),
    //         [3]=log_A_real (H,N2), [4]=A_imag (H,N2)
    const float* C          = (const float*)d_in[1];
    const float* log_dt     = (const float*)d_in[2];
    const float* log_A_real = (const float*)d_in[3];
    const float* A_imag     = (const float*)d_in[4];
    float* K = (float*)d_out;

    const int H = in_sizes[2];            // log_dt has H elements
    const int L = out_size / H;           // output is (H, L)
    const int chunks_per_h = (L + CHUNK - 1) / CHUNK;

    dim3 grid(H * chunks_per_h);
    dim3 block(BLOCK);
    s4d_vand_kernel<<<grid, block, 0, stream>>>(C, log_dt, log_A_real, A_imag,
                                                K, L, chunks_per_h);
}

// Round 11
// 12.056 us; speedup vs baseline: 1.0821x; 1.0821x over previous
//
#include <hip/hip_runtime.h>
#include <math.h>

#define N2V 32
#define BLOCK 512             // 8 waves: one block per h
#define CHUNK 4096            // 128 b-values x 32 a-values

typedef float v2f __attribute__((ext_vector_type(2)));

__global__ __launch_bounds__(BLOCK) void s4d_vand_kernel(
    const float* __restrict__ C,          // (H, N2, 2)
    const float* __restrict__ log_dt,     // (H,)
    const float* __restrict__ log_A_real, // (H, N2)
    const float* __restrict__ A_imag,     // (H, N2)
    float* __restrict__ K,                // (H, L)
    int L, int chunks_per_h)
{
    __shared__ float4 sC[N2V];            // (x, y, 2*Ceff_r, 2*Ceff_i)
    __shared__ float2 sR[N2V];            // r = exp(dtA)
    __shared__ float4 sP4[N2V][64];       // (Pr(2i), Pr(2i+1), Pi(2i), Pi(2i+1))
    __shared__ float  sQre[N2V][32];      //  Re r^(chunk+128a)
    __shared__ float  sQim[N2V][32];      // -Im r^(chunk+128a)

    const int h     = blockIdx.x / chunks_per_h;
    const int chunk = (blockIdx.x % chunks_per_h) * CHUNK;
    const int t     = threadIdx.x;

    // ---- stage 1: per-n constants (accurate math, one-time) ----
    if (t < N2V) {
        const int n = t;
        const float dt = expf(log_dt[h]);
        const float ar = -expf(log_A_real[h * N2V + n]);  // Re(A)
        const float ai = A_imag[h * N2V + n];             // Im(A)
        const float x = ar * dt;                          // Re(dtA)
        const float y = ai * dt;                          // Im(dtA)
        float sn, cs;
        sincosf(y, &sn, &cs);
        const float e  = expf(x);
        const float wr = e * cs - 1.0f;                   // w = exp(dtA)-1
        const float wi = e * sn;
        const float inv = 1.0f / (ar * ar + ai * ai);     // w/A = w*conj(A)/|A|^2
        const float dr = (wr * ar + wi * ai) * inv;
        const float di = (wi * ar - wr * ai) * inv;
        const float cr = C[(h * N2V + n) * 2 + 0];
        const float ci = C[(h * N2V + n) * 2 + 1];
        sC[n] = make_float4(x, y,
                            2.0f * (cr * dr - ci * di),
                            2.0f * (cr * di + ci * dr));
        sR[n] = make_float2(e * cs, e * sn);              // r = exp(dtA)
    }
    __syncthreads();

    // ---- stage 2a: P table, 2048 float4 entries (4 per thread) ----
#pragma unroll
    for (int m = 0; m < 4; ++m) {
        const int e = t + m * BLOCK;          // 0..2047
        const int n = e >> 6;                 // 0..31
        const int i = e & 63;                 // b-pair (2i, 2i+1)
        const float4 c = sC[n];
        const float2 r = sR[n];
        const float fb = (float)(2 * i);
        float sn, cs;
        __sincosf(c.y * fb, &sn, &cs);
        const float ex = __expf(c.x * fb);
        const float ur = ex * cs, ui = ex * sn;           // r^(2i)
        const float p0r = c.z * ur - c.w * ui;            // P(2i) = 2Ceff * r^(2i)
        const float p0i = c.z * ui + c.w * ur;
        const float p1r = p0r * r.x - p0i * r.y;          // P(2i+1) = P(2i) * r
        const float p1i = p0r * r.y + p0i * r.x;
        sP4[n][i] = make_float4(p0r, p1r, p0i, p1i);
    }
    // ---- stage 2b: Q tables, 1024 scalars (2 per thread) ----
#pragma unroll
    for (int m = 0; m < 2; ++m) {
        const int e = t + m * BLOCK;          // 0..1023
        const int n = e >> 5;                 // 0..31
        const int a = e & 31;                 // 0..31
        const float4 c = sC[n];
        const float fl = (float)(chunk + 128 * a);
        float sn, cs;
        __sincosf(c.y * fl, &sn, &cs);
        const float ex = __expf(c.x * fl);
        sQre[n][a] =  ex * cs;
        sQim[n][a] = -ex * sn;
    }
    __syncthreads();

    // ---- main: packed-FMA reduction over n ----
    const int lane = t & 63;                  // b-pair (2*lane, 2*lane+1)
    const int w    = t >> 6;                  // wave id -> a in {4w..4w+3}

    v2f acc[4];
#pragma unroll
    for (int j = 0; j < 4; ++j) acc[j] = (v2f){0.0f, 0.0f};

    // unroll 2 only: wide unrolls blew VGPR to 256 + spills in round 4.
#pragma unroll 2
    for (int n = 0; n < N2V; ++n) {
        const float4 pp = sP4[n][lane];       // per-lane b128 (2 b, re+im)
        const float4 qr = ((const float4*)&sQre[n][0])[w];  // broadcast b128
        const float4 qi = ((const float4*)&sQim[n][0])[w];  // broadcast b128
        const v2f prr = {pp.x, pp.y};         // (Pr at b0, Pr at b1)
        const v2f pii = {pp.z, pp.w};         // (Pi at b0, Pi at b1)
        acc[0] = __builtin_elementwise_fma(prr, (v2f){qr.x, qr.x},
                 __builtin_elementwise_fma(pii, (v2f){qi.x, qi.x}, acc[0]));
        acc[1] = __builtin_elementwise_fma(prr, (v2f){qr.y, qr.y},
                 __builtin_elementwise_fma(pii, (v2f){qi.y, qi.y}, acc[1]));
        acc[2] = __builtin_elementwise_fma(prr, (v2f){qr.z, qr.z},
                 __builtin_elementwise_fma(pii, (v2f){qi.z, qi.z}, acc[2]));
        acc[3] = __builtin_elementwise_fma(prr, (v2f){qr.w, qr.w},
                 __builtin_elementwise_fma(pii, (v2f){qi.w, qi.w}, acc[3]));
    }

    // ---- store: acc[j] = (K(2lane, a), K(2lane+1, a)), a = 4w+j ----
    float* out = K + (size_t)h * L + chunk + 2 * lane;
#pragma unroll
    for (int j = 0; j < 4; ++j) {
        const int a  = 4 * w + j;
        const int l0 = chunk + 2 * lane + 128 * a;
        if (l0 < L)   // L even, l0 even -> the pair fits
            *reinterpret_cast<float2*>(out + (size_t)128 * a) =
                make_float2(acc[j].x, acc[j].y);
    }
}

extern "C" void kernel_launch(void* const* d_in, const int* in_sizes, int n_in,
                              void* d_out, int out_size, void* d_ws, size_t ws_size,
                              hipStream_t stream) {
    // inputs: [0]=L (scalar), [1]=C (H,N2,2), [2]=log_dt (H,),
    //         [3]=log_A_real (H,N2), [4]=A_imag (H,N2)
    const float* C          = (const float*)d_in[1];
    const float* log_dt     = (const float*)d_in[2];
    const float* log_A_real = (const float*)d_in[3];
    const float* A_imag     = (const float*)d_in[4];
    float* K = (float*)d_out;

    const int H = in_sizes[2];            // log_dt has H elements
    const int L = out_size / H;           // output is (H, L)
    const int chunks_per_h = (L + CHUNK - 1) / CHUNK;

    dim3 grid(H * chunks_per_h);
    dim3 block(BLOCK);
    s4d_vand_kernel<<<grid, block, 0, stream>>>(C, log_dt, log_A_real, A_imag,
                                                K, L, chunks_per_h);
}